// Round 14
// baseline (110.340 us; speedup 1.0000x reference)
//
#include <hip/hip_runtime.h>
#include <hip/hip_bf16.h>

#define S_LEN 2048
#define NH 16
#define HD 64
#define DM 1024
#define BATCH 2
#define M_ROWS (BATCH * S_LEN)  // 4096
#define SCALE2 0.18033688011112043f  /* 0.125 * log2(e) */
#define M2FIX 8.0f

typedef float f32x4 __attribute__((ext_vector_type(4)));
typedef float f32x16 __attribute__((ext_vector_type(16)));
typedef __bf16 bf16x8 __attribute__((ext_vector_type(8)));
typedef short short8 __attribute__((ext_vector_type(8)));

__device__ __forceinline__ unsigned short f2bf(float f) {
  unsigned u = __builtin_bit_cast(unsigned, f);
  u += 0x7FFFu + ((u >> 16) & 1u);
  return (unsigned short)(u >> 16);
}

__device__ __forceinline__ f32x4 mfma16(bf16x8 a, bf16x8 b, f32x4 c) {
  return __builtin_amdgcn_mfma_f32_16x16x32_bf16(a, b, c, 0, 0, 0);
}

__device__ __forceinline__ f32x16 mfma32(bf16x8 a, bf16x8 b, f32x16 c) {
  return __builtin_amdgcn_mfma_f32_32x32x16_bf16(a, b, c, 0, 0, 0);
}

__device__ __forceinline__ void gload_lds16(const void* g, void* l) {
  __builtin_amdgcn_global_load_lds(
      (const __attribute__((address_space(1))) void*)g,
      (__attribute__((address_space(3))) void*)l, 16, 0, 0);
}

// ---------------- cast x -> bf16 (vectorized) ----------------
__global__ __launch_bounds__(256) void cast_bf16_kernel(
    const float* __restrict__ in, unsigned short* __restrict__ out) {
  int i = blockIdx.x * 256 + threadIdx.x;  // each handles 8 elems
  const float4* p = (const float4*)in;
  float4 f0 = p[i * 2], f1 = p[i * 2 + 1];
  short8 o;
  o[0] = (short)f2bf(f0.x); o[1] = (short)f2bf(f0.y);
  o[2] = (short)f2bf(f0.z); o[3] = (short)f2bf(f0.w);
  o[4] = (short)f2bf(f1.x); o[5] = (short)f2bf(f1.y);
  o[6] = (short)f2bf(f1.z); o[7] = (short)f2bf(f1.w);
  ((short8*)out)[i] = o;
}

// ---------------- transpose + cast weights: Wt[n][k] = bf16(W[k][n]) ----------------
__global__ __launch_bounds__(256) void transpose_cast_kernel(
    const float* __restrict__ W0, const float* __restrict__ W1,
    const float* __restrict__ W2, const float* __restrict__ W3,
    unsigned short* __restrict__ out) {
  int z = blockIdx.z;
  const float* W = (z == 0) ? W0 : (z == 1) ? W1 : (z == 2) ? W2 : W3;
  __shared__ float tile[32][33];
  int tx = threadIdx.x & 31, ty = threadIdx.x >> 5;  // 32 x 8
  int bx = blockIdx.x * 32, by = blockIdx.y * 32;
#pragma unroll
  for (int i = 0; i < 4; ++i)
    tile[ty + i * 8][tx] = W[(size_t)(by + ty + i * 8) * DM + bx + tx];
  __syncthreads();
  unsigned short* o = out + (size_t)z * DM * DM;
#pragma unroll
  for (int i = 0; i < 4; ++i)
    o[(size_t)(bx + ty + i * 8) * DM + by + tx] = f2bf(tile[tx][ty + i * 8]);
}

// ---------------- QKV GEMM, 256x256 tile, phase-split schedule ----------------
// BM=BN=256, BK=32, 512 threads (8 waves: wr=wid>>2, wc=wid&3; per-wave out
// 128x64). 3-slot K-tile pipeline: stage K-tile j+2 during group j (2-group
// lead), counted vmcnt(4) at group boundary. Each K-tile = 2 phases x 16 MFMA
// with per-phase {ds_read || stage-issue || barrier || lgkmcnt(0) || setprio}.
// LDS swizzle: A/B tiles stored as [128 prow][8 slot16]; slot for global
// (row,kchunk g) = ((row&1)*4+g) ^ (prow&7) -> frag reads are 2 lanes/bank.
// Epilogue: Q (cols 0..1023) pre-scaled by SCALE2; K bf16; V written
// TRANSPOSED per head via two-pass LDS transpose: Vt[((b*16+h)*64+d)*2048+s].
__global__ __launch_bounds__(512, 2) void gemm_qkv256_kernel(
    const unsigned short* __restrict__ A, const unsigned short* __restrict__ Bt,
    unsigned short* __restrict__ Cb, const float* __restrict__ bQ,
    const float* __restrict__ bK, const float* __restrict__ bV) {
  const int t = threadIdx.x, lane = t & 63;
  const int wid = t >> 6, wr = wid >> 2, wc = wid & 3;
  const int r16 = lane & 15, g = lane >> 4;
  const int K = 1024, nk = 32;

  // block decode: 192 blocks; XCD xcd owns m-tiles {2xcd, 2xcd+1} x all 12 n
  const int lid = blockIdx.x;
  const int xcd = lid & 7, idx = lid >> 3;  // idx 0..23
  const int by = xcd * 2 + (idx >= 12);
  const int bx = (idx >= 12) ? idx - 12 : idx;
  const int m0 = by * 256, n0 = bx * 256;

  __shared__ __align__(16) char LB[98304];  // A 3x16KB | B 3x16KB (union: T)

  // staging: chunk c (0..1023): prow=c>>3, s16=c&7, v=s16^(prow&7),
  // row=2*prow+(v>>2), kchunk=v&3. Thread t handles c0=t, c1=t+512.
  const int c0 = t, c1 = t + 512;
  const int pr0 = c0 >> 3, v0 = (c0 & 7) ^ (pr0 & 7);
  const int pr1 = c1 >> 3, v1 = (c1 & 7) ^ (pr1 & 7);
  const int ar0 = 2 * pr0 + (v0 >> 2), ak0 = (v0 & 3) * 8;
  const int ar1 = 2 * pr1 + (v1 >> 2), ak1 = (v1 & 3) * 8;

#define ASLOT(s) ((unsigned short*)(LB + (s) * 16384))
#define BSLOT(s) ((unsigned short*)(LB + 49152 + (s) * 16384))
#define STAGE_A(s, k0)                                                        \
  gload_lds16(A + (size_t)(m0 + ar0) * K + (k0) + ak0, ASLOT(s) + c0 * 8);    \
  gload_lds16(A + (size_t)(m0 + ar1) * K + (k0) + ak1, ASLOT(s) + c1 * 8);
#define STAGE_B(s, k0)                                                        \
  gload_lds16(Bt + (size_t)(n0 + ar0) * K + (k0) + ak0, BSLOT(s) + c0 * 8);   \
  gload_lds16(Bt + (size_t)(n0 + ar1) * K + (k0) + ak1, BSLOT(s) + c1 * 8);

  // fragment read: byte = (rowbase/2 + r16>>1)*128 + S16*16
  const int S16 = ((r16 & 1) * 4 + g) ^ (r16 >> 1);
  const int aoff = (r16 >> 1) * 128 + S16 * 16;  // bytes

  f32x4 acc[8][4] = {};

  STAGE_A(0, 0); STAGE_B(0, 0);
  STAGE_A(1, 32); STAGE_B(1, 32);
  asm volatile("s_waitcnt vmcnt(4)" ::: "memory");
  __builtin_amdgcn_s_barrier();

  for (int j = 0; j < nk; ++j) {
    const int cs = j % 3, ps = (j + 2) % 3;
    const char* As_ = (const char*)ASLOT(cs);
    const char* Bs_ = (const char*)BSLOT(cs);

    // ---- phase 0: M-frags 0..3 x N-frags 0..3 ----
    bf16x8 af[4], bf[4];
#pragma unroll
    for (int mi = 0; mi < 4; ++mi)
      af[mi] = *(const bf16x8*)(As_ + (wr * 64 + mi * 8) * 128 + aoff);
#pragma unroll
    for (int ni = 0; ni < 4; ++ni)
      bf[ni] = *(const bf16x8*)(Bs_ + (wc * 32 + ni * 8) * 128 + aoff);
    if (j + 2 < nk) { STAGE_A(ps, (j + 2) * 32); }
    __builtin_amdgcn_s_barrier();
    asm volatile("s_waitcnt lgkmcnt(0)" ::: "memory");
    __builtin_amdgcn_s_setprio(1);
#pragma unroll
    for (int mi = 0; mi < 4; ++mi)
#pragma unroll
      for (int ni = 0; ni < 4; ++ni)
        acc[mi][ni] = mfma16(af[mi], bf[ni], acc[mi][ni]);
    __builtin_amdgcn_s_setprio(0);
    __builtin_amdgcn_s_barrier();

    // ---- phase 1: M-frags 4..7 x N-frags 0..3 (B reused) ----
    bf16x8 af2[4];
#pragma unroll
    for (int mi = 0; mi < 4; ++mi)
      af2[mi] = *(const bf16x8*)(As_ + (wr * 64 + 32 + mi * 8) * 128 + aoff);
    if (j + 2 < nk) { STAGE_B(ps, (j + 2) * 32); }
    __builtin_amdgcn_s_barrier();
    asm volatile("s_waitcnt lgkmcnt(0)" ::: "memory");
    __builtin_amdgcn_s_setprio(1);
#pragma unroll
    for (int mi = 0; mi < 4; ++mi)
#pragma unroll
      for (int ni = 0; ni < 4; ++ni)
        acc[4 + mi][ni] = mfma16(af2[mi], bf[ni], acc[4 + mi][ni]);
    __builtin_amdgcn_s_setprio(0);

    // group end: publish next K-tile landing (counted vmcnt, never 0 mid-loop)
    if (j + 1 < nk) {
      if (j + 2 < nk) {
        asm volatile("s_waitcnt vmcnt(4)" ::: "memory");
      } else {
        asm volatile("s_waitcnt vmcnt(0)" ::: "memory");
      }
    }
    __builtin_amdgcn_s_barrier();
  }
#undef STAGE_A
#undef STAGE_B

  // ---------------- epilogue ----------------
  const int bufq = n0 >> 10;  // 0=Q 1=K 2=V (n0 multiple of 256; regions 1024)
  if (bufq < 2) {
    const float* bp = bufq ? bK : bQ;
    const float sc = bufq ? 1.0f : SCALE2;
#pragma unroll
    for (int ni = 0; ni < 4; ++ni) {
      int cn = (n0 & 1023) + wc * 64 + ni * 16 + r16;
      float bv = bp[cn];
#pragma unroll
      for (int mi = 0; mi < 8; ++mi) {
        int row = m0 + wr * 128 + mi * 16 + 4 * g;
#pragma unroll
        for (int jj = 0; jj < 4; ++jj)
          Cb[(size_t)bufq * 4194304u + (size_t)(row + jj) * 1024 + cn] =
              __builtin_bit_cast(unsigned short, (__bf16)((acc[mi][ni][jj] + bv) * sc));
      }
    }
  } else {
    // V: 256(s) x 256(hd) tile -> V^T in two 128-col passes through LDS
    unsigned short* T = (unsigned short*)LB;  // [128 cnl][264] shorts = 67.6KB
    const int bb = m0 >> 11, s0g = m0 & 2047;
    unsigned short* Vt = Cb + 8388608u;
#pragma unroll
    for (int ph = 0; ph < 2; ++ph) {
      __syncthreads();
      if ((wc >> 1) == ph) {
#pragma unroll
        for (int ni = 0; ni < 4; ++ni) {
          int cnl = (wc & 1) * 64 + ni * 16 + r16;  // 0..127
          float bv = bV[(n0 & 1023) + ph * 128 + cnl];
#pragma unroll
          for (int mi = 0; mi < 8; ++mi) {
            int sl = wr * 128 + mi * 16 + 4 * g;
            union { __bf16 h4[4]; uint2 u; } cv;
#pragma unroll
            for (int jj = 0; jj < 4; ++jj) cv.h4[jj] = (__bf16)(acc[mi][ni][jj] + bv);
            *(uint2*)&T[cnl * 264 + sl] = cv.u;
          }
        }
      }
      __syncthreads();
#pragma unroll
      for (int q = 0; q < 8; ++q) {
        int idx2 = q * 512 + t;
        int cnl = idx2 >> 5, sch = idx2 & 31;
        int cng = (n0 & 1023) + ph * 128 + cnl;
        int hh = cng >> 6, d = cng & 63;
        short8 v = *(const short8*)&T[cnl * 264 + sch * 8];
        *(short8*)&Vt[(((size_t)((bb * 16 + hh) * 64 + d)) << 11) + s0g + sch * 8] = v;
      }
    }
  }
}

// ---------------- output-projection GEMM (128^2, proven): C = A * Bt^T + b ----------
__global__ __launch_bounds__(256) void gemm_out_kernel(
    const unsigned short* __restrict__ A, const unsigned short* __restrict__ Bt,
    float* __restrict__ Cf, const float* __restrict__ bias0, int M, int N, int K) {
  __shared__ __align__(16) unsigned short As[3][4096];
  __shared__ __align__(16) unsigned short Bs[3][4096];
  const int t = threadIdx.x, lane = t & 63;
  const int wid = t >> 6, wr = wid >> 1, wc = wid & 1;
  const int r16 = lane & 15, g = lane >> 4;
  const int m0 = blockIdx.y * 128, n0 = blockIdx.x * 128;
  const int nk = K >> 5;

  const int n1 = t, n2 = t + 256;
  const int r1g = t >> 2;
  const int r2g = r1g + 64;
  const int c1g = ((t & 3) ^ (r1g & 3)) * 8;

  const unsigned short* ap1 = A + (size_t)(m0 + r1g) * K + c1g;
  const unsigned short* ap2 = A + (size_t)(m0 + r2g) * K + c1g;
  const unsigned short* bp1 = Bt + (size_t)(n0 + r1g) * K + c1g;
  const unsigned short* bp2 = Bt + (size_t)(n0 + r2g) * K + c1g;

#define GSTAGE(s)                          \
  gload_lds16(ap1, &As[s][n1 * 8]);        \
  gload_lds16(bp1, &Bs[s][n1 * 8]);        \
  gload_lds16(ap2, &As[s][n2 * 8]);        \
  gload_lds16(bp2, &Bs[s][n2 * 8]);        \
  ap1 += 32; ap2 += 32; bp1 += 32; bp2 += 32;

  f32x4 acc[4][4] = {};
  GSTAGE(0);
  GSTAGE(1);

  const int axr = ((g ^ (r16 & 3)) * 8);

  for (int kt = 0; kt < nk; ++kt) {
    const int cs = kt % 3;
    if (kt + 1 < nk) {
      asm volatile("s_waitcnt vmcnt(4)" ::: "memory");
    } else {
      asm volatile("s_waitcnt vmcnt(0)" ::: "memory");
    }
    __builtin_amdgcn_s_barrier();
    if (kt + 2 < nk) { GSTAGE((kt + 2) % 3); }

    bf16x8 af[4], bfr[4];
#pragma unroll
    for (int mi = 0; mi < 4; ++mi)
      af[mi] = *(const bf16x8*)&As[cs][(wr * 64 + mi * 16 + r16) * 32 + axr];
#pragma unroll
    for (int ni = 0; ni < 4; ++ni)
      bfr[ni] = *(const bf16x8*)&Bs[cs][(wc * 64 + ni * 16 + r16) * 32 + axr];
    __builtin_amdgcn_s_setprio(1);
#pragma unroll
    for (int mi = 0; mi < 4; ++mi)
#pragma unroll
      for (int ni = 0; ni < 4; ++ni)
        acc[mi][ni] = mfma16(af[mi], bfr[ni], acc[mi][ni]);
    __builtin_amdgcn_s_setprio(0);
  }
#undef GSTAGE

#pragma unroll
  for (int ni = 0; ni < 4; ++ni) {
    int col = n0 + wc * 64 + ni * 16 + r16;
    float bv = bias0[col];
#pragma unroll
    for (int mi = 0; mi < 4; ++mi) {
      int rowb = m0 + wr * 64 + mi * 16 + 4 * g;
#pragma unroll
      for (int j = 0; j < 4; ++j)
        Cf[(size_t)(rowb + j) * N + col] = acc[mi][ni][j] + bv;
    }
  }
}

// ---------------- flash attention v11 (reverted best): 32x32 MFMA, kv-split ---------
// grid 512 x 256. Block = 64 q-rows; sequential halves {mq, 31-mq} -> uniform 17
// 128-wide kv iterations. Wave w owns kv quarter w*32 and BOTH 32-q output tiles.
// P stays in registers via 4 permlane32_swap per q-tile. Cross-wave O-reduction
// through padded LDS once per half. Dbuf K/V staging, vmcnt(0)+barrier per iter.
// Fixed-shift exp2 softmax (m=8, exact). XCD decode keeps K/V L2-resident.
__global__ __launch_bounds__(256, 2) void attn_kernel(
    const unsigned short* __restrict__ Qm, const unsigned short* __restrict__ Km,
    const unsigned short* __restrict__ VtG, unsigned short* __restrict__ Om) {
  const int t = threadIdx.x, lane = t & 63, w = t >> 6;
  const int l31 = lane & 31, hi = lane >> 5;
  const int bid = blockIdx.x;
  const int xk = bid & 7, slot = bid >> 3;
  const int grp = xk * 4 + (slot >> 4);  // (b,h) group, 4 per XCD
  const int mq = slot & 15;
  const int h = grp & 15, b = grp >> 4;

  __shared__ __align__(16) char LB[71680];
  float* R = (float*)LB;
  float* ls = (float*)(LB + 69632);

  const unsigned short* Kbase = Km + (size_t)(b * S_LEN) * DM + h * HD;
  const unsigned short* Vbase = VtG + (size_t)((b * NH + h) * HD) * S_LEN;

  const int kg = ((t & 7) ^ ((t >> 3) & 7)) * 8;
  const int kr0 = t >> 3;
  const int vg = ((t & 15) ^ ((t >> 4) & 15)) * 8;
  const int vr0 = t >> 4;

  auto stage = [&](int cs, int kv0) {
    unsigned short* kd = (unsigned short*)(LB + cs * 16384) + t * 8;
    unsigned short* vd = (unsigned short*)(LB + 32768 + cs * 16384) + t * 8;
#pragma unroll
    for (int p = 0; p < 4; ++p)
      gload_lds16(Kbase + (size_t)(kv0 + kr0 + 32 * p) * DM + kg, kd + 2048 * p);
#pragma unroll
    for (int p = 0; p < 4; ++p)
      gload_lds16(Vbase + (size_t)(vr0 + 16 * p) * S_LEN + kv0 + vg, vd + 2048 * p);
  };

  for (int half = 0; half < 2; ++half) {
    const int T = half ? 31 - mq : mq;
    const int q0 = T * 64;

    bf16x8 qfr[2][4];
#pragma unroll
    for (int qt = 0; qt < 2; ++qt) {
      const unsigned short* Qp =
          Qm + (size_t)(b * S_LEN + q0 + qt * 32 + l31) * DM + h * HD;
#pragma unroll
      for (int kc = 0; kc < 4; ++kc)
        qfr[qt][kc] = *(const bf16x8*)(Qp + kc * 16 + hi * 8);
    }

    f32x16 oacc[2][2] = {};
    float lsum0 = 0.f, lsum1 = 0.f;
    const int ntk = (T >> 1) + 1;

    stage(0, 0);

    for (int kt = 0; kt < ntk; ++kt) {
      const int cs = kt & 1;
      asm volatile("s_waitcnt vmcnt(0)" ::: "memory");
      __builtin_amdgcn_s_barrier();
      if (kt + 1 < ntk) stage(cs ^ 1, (kt + 1) * 128);

      const int kv0w = kt * 128 + w * 32;
      if (kv0w <= q0 + 63) {
        const unsigned short* Ksb = (const unsigned short*)(LB + cs * 16384);
        const unsigned short* Vsb = (const unsigned short*)(LB + 32768 + cs * 16384);

        bf16x8 kf[4];
#pragma unroll
        for (int kc = 0; kc < 4; ++kc)
          kf[kc] = *(const bf16x8*)&Ksb[(w * 32 + l31) * 64 +
                                        (((hi + 2 * kc) ^ (lane & 7)) * 8)];
        bool act0 = false, act1 = false;
        bf16x8 pfr[2][2];
#pragma unroll
        for (int qt = 0; qt < 2; ++qt) {
          const bool act = (kv0w <= q0 + qt * 32 + 31);
          if (qt == 0) act0 = act; else act1 = act;
          if (!act) continue;
          f32x16 st = {};
          __builtin_amdgcn_s_setprio(1);
#pragma unroll
          for (int kc = 0; kc < 4; ++kc) st = mfma32(kf[kc], qfr[qt][kc], st);
          __builtin_amdgcn_s_setprio(0);

          const bool needmask = (kv0w + 31 > q0 + qt * 32);
          const int qg = q0 + qt * 32 + l31;
          float p[16];
          float ps = 0.f;
#pragma unroll
          for (int r = 0; r < 16; ++r) {
            int row = (r & 3) + 8 * (r >> 2) + 4 * hi;
            float v = __builtin_amdgcn_exp2f(st[r] - M2FIX);
            if (needmask && (kv0w + row > qg)) v = 0.f;
            p[r] = v;
            ps += v;
          }
          if (qt == 0) lsum0 += ps; else lsum1 += ps;

          unsigned pw[8];
#pragma unroll
          for (int r = 0; r < 8; ++r) {
            union { __bf16 h2[2]; unsigned u; } cv;
            cv.h2[0] = (__bf16)p[2 * r];
            cv.h2[1] = (__bf16)p[2 * r + 1];
            pw[r] = cv.u;
          }
          {
            auto s0 = __builtin_amdgcn_permlane32_swap(pw[0], pw[2], false, false);
            pw[0] = s0[0]; pw[2] = s0[1];
            auto s1 = __builtin_amdgcn_permlane32_swap(pw[1], pw[3], false, false);
            pw[1] = s1[0]; pw[3] = s1[1];
            auto s2 = __builtin_amdgcn_permlane32_swap(pw[4], pw[6], false, false);
            pw[4] = s2[0]; pw[6] = s2[1];
            auto s3 = __builtin_amdgcn_permlane32_swap(pw[5], pw[7], false, false);
            pw[5] = s3[0]; pw[7] = s3[1];
          }
          union { unsigned u[4]; bf16x8 v; } f0, f1;
          f0.u[0] = pw[0]; f0.u[1] = pw[1]; f0.u[2] = pw[2]; f0.u[3] = pw[3];
          f1.u[0] = pw[4]; f1.u[1] = pw[5]; f1.u[2] = pw[6]; f1.u[3] = pw[7];
          pfr[qt][0] = f0.v;
          pfr[qt][1] = f1.v;
        }

        bf16x8 vf[2][2];
#pragma unroll
        for (int dt = 0; dt < 2; ++dt)
#pragma unroll
          for (int ks = 0; ks < 2; ++ks)
            vf[dt][ks] = *(const bf16x8*)&Vsb[(dt * 32 + l31) * 128 +
                                              (((4 * w + 2 * ks + hi) ^ (lane & 15)) * 8)];
        __builtin_amdgcn_s_setprio(1);
        if (act0) {
#pragma unroll
          for (int dt = 0; dt < 2; ++dt) {
            oacc[dt][0] = mfma32(vf[dt][0], pfr[0][0], oacc[dt][0]);
            oacc[dt][0] = mfma32(vf[dt][1], pfr[0][1], oacc[dt][0]);
          }
        }
        if (act1) {
#pragma unroll
          for (int dt = 0; dt < 2; ++dt) {
            oacc[dt][1] = mfma32(vf[dt][0], pfr[1][0], oacc[dt][1]);
            oacc[dt][1] = mfma32(vf[dt][1], pfr[1][1], oacc[dt][1]);
          }
        }
        __builtin_amdgcn_s_setprio(0);
      }
    }

    __syncthreads();
    float* Rw = R + w * 4352;
#pragma unroll
    for (int dt = 0; dt < 2; ++dt)
#pragma unroll
      for (int qt = 0; qt < 2; ++qt) {
        int q = qt * 32 + l31;
#pragma unroll
        for (int r = 0; r < 16; r += 2) {
          int d = dt * 32 + ((r & 3) + 8 * (r >> 2)) + 4 * hi;
          float2 v2;
          v2.x = oacc[dt][qt][r];
          v2.y = oacc[dt][qt][r + 1];
          *(float2*)&Rw[q * 68 + d] = v2;
        }
      }
    ls[(w * 64 + l31) * 2 + hi] = lsum0;
    ls[(w * 64 + 32 + l31) * 2 + hi] = lsum1;
    __syncthreads();

    const int rq = t >> 2, dq = (t & 3) * 16;
    f32x4 a0 = {}, a1 = {}, a2 = {}, a3 = {};
#pragma unroll
    for (int w4 = 0; w4 < 4; ++w4) {
      const float* Rb = R + w4 * 4352 + rq * 68 + dq;
      a0 += *(const f32x4*)&Rb[0];
      a1 += *(const f32x4*)&Rb[4];
      a2 += *(const f32x4*)&Rb[8];
      a3 += *(const f32x4*)&Rb[12];
    }
    float s = 0.f;
#pragma unroll
    for (int w4 = 0; w4 < 4; ++w4)
      s += ls[(w4 * 64 + rq) * 2] + ls[(w4 * 64 + rq) * 2 + 1];
    float li = 1.0f / s;
    unsigned short* op = Om + (size_t)(b * S_LEN + q0 + rq) * DM + h * HD + dq;
    union { __bf16 hh[8]; uint4 u; } o0, o1;
#pragma unroll
    for (int i = 0; i < 4; ++i) {
      o0.hh[i] = (__bf16)(a0[i] * li);
      o0.hh[4 + i] = (__bf16)(a1[i] * li);
      o1.hh[i] = (__bf16)(a2[i] * li);
      o1.hh[4 + i] = (__bf16)(a3[i] * li);
    }
    *(uint4*)op = o0.u;
    *(uint4*)(op + 8) = o1.u;
    __syncthreads();
  }
}

extern "C" void kernel_launch(void* const* d_in, const int* in_sizes, int n_in,
                              void* d_out, int out_size, void* d_ws, size_t ws_size,
                              hipStream_t stream) {
  (void)in_sizes; (void)n_in; (void)out_size; (void)ws_size;
  const float* x  = (const float*)d_in[0];
  const float* WQ = (const float*)d_in[1];
  const float* WK = (const float*)d_in[2];
  const float* WV = (const float*)d_in[3];
  const float* WO = (const float*)d_in[4];
  const float* bQ = (const float*)d_in[5];
  const float* bK = (const float*)d_in[6];
  const float* bV = (const float*)d_in[7];
  const float* bO = (const float*)d_in[8];

  char* ws = (char*)d_ws;
  unsigned short* xb  = (unsigned short*)(ws);               // 8 MiB (x bf16)
  unsigned short* wt  = (unsigned short*)(ws + (8u << 20));  // 8 MiB (Wq|Wk|Wv|Wo)^T
  unsigned short* qb  = (unsigned short*)(ws + (16u << 20)); // 24 MiB (Q | K | V^T)
  unsigned short* hsb = (unsigned short*)(ws + (40u << 20)); // 8 MiB (attn out)

  cast_bf16_kernel<<<2048, 256, 0, stream>>>(x, xb);
  transpose_cast_kernel<<<dim3(32, 32, 4), 256, 0, stream>>>(WQ, WK, WV, WO, wt);
  // fused QKV projection (256^2 phase-split): Q pre-scaled, V^T epilogue
  gemm_qkv256_kernel<<<192, 512, 0, stream>>>(xb, wt, qb, bQ, bK, bV);
  attn_kernel<<<512, 256, 0, stream>>>(qb, qb + 4194304u, qb + 8388608u, hsb);
  // output projection: f32 out
  gemm_out_kernel<<<dim3(8, 32), 256, 0, stream>>>(
      hsb, wt + 3u * 1048576u, (float*)d_out, bO, M_ROWS, DM, DM);
}

// Round 15
// 107.225 us; speedup vs baseline: 1.0291x; 1.0291x over previous
//
#include <hip/hip_runtime.h>
#include <hip/hip_bf16.h>

#define S_LEN 2048
#define NH 16
#define HD 64
#define DM 1024
#define BATCH 2
#define M_ROWS (BATCH * S_LEN)  // 4096
#define SCALE2 0.18033688011112043f  /* 0.125 * log2(e) */
#define M2FIX 8.0f

typedef float f32x4 __attribute__((ext_vector_type(4)));
typedef float f32x16 __attribute__((ext_vector_type(16)));
typedef __bf16 bf16x8 __attribute__((ext_vector_type(8)));
typedef short short8 __attribute__((ext_vector_type(8)));

__device__ __forceinline__ unsigned short f2bf(float f) {
  unsigned u = __builtin_bit_cast(unsigned, f);
  u += 0x7FFFu + ((u >> 16) & 1u);
  return (unsigned short)(u >> 16);
}

__device__ __forceinline__ f32x4 mfma16(bf16x8 a, bf16x8 b, f32x4 c) {
  return __builtin_amdgcn_mfma_f32_16x16x32_bf16(a, b, c, 0, 0, 0);
}

__device__ __forceinline__ f32x16 mfma32(bf16x8 a, bf16x8 b, f32x16 c) {
  return __builtin_amdgcn_mfma_f32_32x32x16_bf16(a, b, c, 0, 0, 0);
}

__device__ __forceinline__ void gload_lds16(const void* g, void* l) {
  __builtin_amdgcn_global_load_lds(
      (const __attribute__((address_space(1))) void*)g,
      (__attribute__((address_space(3))) void*)l, 16, 0, 0);
}

// ---------------- prep: cast x -> bf16 (z=0) + transpose/cast weights (z=1..4) -------
__global__ __launch_bounds__(256) void prep_kernel(
    const float* __restrict__ x, const float* __restrict__ W0,
    const float* __restrict__ W1, const float* __restrict__ W2,
    const float* __restrict__ W3, unsigned short* __restrict__ xb,
    unsigned short* __restrict__ wt) {
  const int z = blockIdx.z;
  if (z == 0) {
    // cast: 1024 xy-blocks x 256 threads x 16 f32 = 4096*1024 elems
    int i = ((blockIdx.y * 32 + blockIdx.x) * 256 + threadIdx.x) * 2;
    const float4* p = (const float4*)x;
#pragma unroll
    for (int c = 0; c < 2; ++c) {
      float4 f0 = p[(i + c) * 2], f1 = p[(i + c) * 2 + 1];
      short8 o;
      o[0] = (short)f2bf(f0.x); o[1] = (short)f2bf(f0.y);
      o[2] = (short)f2bf(f0.z); o[3] = (short)f2bf(f0.w);
      o[4] = (short)f2bf(f1.x); o[5] = (short)f2bf(f1.y);
      o[6] = (short)f2bf(f1.z); o[7] = (short)f2bf(f1.w);
      ((short8*)xb)[i + c] = o;
    }
    return;
  }
  // weight transpose+cast: Wt[n][k] = bf16(W[k][n])
  const float* W = (z == 1) ? W0 : (z == 2) ? W1 : (z == 3) ? W2 : W3;
  __shared__ float tile[32][33];
  int tx = threadIdx.x & 31, ty = threadIdx.x >> 5;  // 32 x 8
  int bx = blockIdx.x * 32, by = blockIdx.y * 32;
#pragma unroll
  for (int i = 0; i < 4; ++i)
    tile[ty + i * 8][tx] = W[(size_t)(by + ty + i * 8) * DM + bx + tx];
  __syncthreads();
  unsigned short* o = wt + (size_t)(z - 1) * DM * DM;
#pragma unroll
  for (int i = 0; i < 4; ++i)
    o[(size_t)(bx + ty + i * 8) * DM + by + tx] = f2bf(tile[tx][ty + i * 8]);
}

// ---------------- QKV GEMM, 256x256 tile, phase-split schedule (r14, kept) ----------
// BM=BN=256, BK=32, 512 threads (8 waves). 3-slot K-tile pipeline, counted
// vmcnt(4) at group boundary; 2 phases x 16 MFMA per K-tile. Swizzled LDS.
// Epilogue: Q pre-scaled by SCALE2; K bf16; V written transposed per head via
// two-pass LDS transpose: Vt[((b*16+h)*64+d)*2048+s].
__global__ __launch_bounds__(512, 2) void gemm_qkv256_kernel(
    const unsigned short* __restrict__ A, const unsigned short* __restrict__ Bt,
    unsigned short* __restrict__ Cb, const float* __restrict__ bQ,
    const float* __restrict__ bK, const float* __restrict__ bV) {
  const int t = threadIdx.x, lane = t & 63;
  const int wid = t >> 6, wr = wid >> 2, wc = wid & 3;
  const int r16 = lane & 15, g = lane >> 4;
  const int K = 1024, nk = 32;

  const int lid = blockIdx.x;
  const int xcd = lid & 7, idx = lid >> 3;  // idx 0..23
  const int by = xcd * 2 + (idx >= 12);
  const int bx = (idx >= 12) ? idx - 12 : idx;
  const int m0 = by * 256, n0 = bx * 256;

  __shared__ __align__(16) char LB[98304];  // A 3x16KB | B 3x16KB (union: T)

  const int c0 = t, c1 = t + 512;
  const int pr0 = c0 >> 3, v0 = (c0 & 7) ^ (pr0 & 7);
  const int pr1 = c1 >> 3, v1 = (c1 & 7) ^ (pr1 & 7);
  const int ar0 = 2 * pr0 + (v0 >> 2), ak0 = (v0 & 3) * 8;
  const int ar1 = 2 * pr1 + (v1 >> 2), ak1 = (v1 & 3) * 8;

#define ASLOT(s) ((unsigned short*)(LB + (s) * 16384))
#define BSLOT(s) ((unsigned short*)(LB + 49152 + (s) * 16384))
#define STAGE_A(s, k0)                                                        \
  gload_lds16(A + (size_t)(m0 + ar0) * K + (k0) + ak0, ASLOT(s) + c0 * 8);    \
  gload_lds16(A + (size_t)(m0 + ar1) * K + (k0) + ak1, ASLOT(s) + c1 * 8);
#define STAGE_B(s, k0)                                                        \
  gload_lds16(Bt + (size_t)(n0 + ar0) * K + (k0) + ak0, BSLOT(s) + c0 * 8);   \
  gload_lds16(Bt + (size_t)(n0 + ar1) * K + (k0) + ak1, BSLOT(s) + c1 * 8);

  const int S16 = ((r16 & 1) * 4 + g) ^ (r16 >> 1);
  const int aoff = (r16 >> 1) * 128 + S16 * 16;  // bytes

  f32x4 acc[8][4] = {};

  STAGE_A(0, 0); STAGE_B(0, 0);
  STAGE_A(1, 32); STAGE_B(1, 32);
  asm volatile("s_waitcnt vmcnt(4)" ::: "memory");
  __builtin_amdgcn_s_barrier();

  for (int j = 0; j < nk; ++j) {
    const int cs = j % 3, ps = (j + 2) % 3;
    const char* As_ = (const char*)ASLOT(cs);
    const char* Bs_ = (const char*)BSLOT(cs);

    // ---- phase 0: M-frags 0..3 x N-frags 0..3 ----
    bf16x8 af[4], bf[4];
#pragma unroll
    for (int mi = 0; mi < 4; ++mi)
      af[mi] = *(const bf16x8*)(As_ + (wr * 64 + mi * 8) * 128 + aoff);
#pragma unroll
    for (int ni = 0; ni < 4; ++ni)
      bf[ni] = *(const bf16x8*)(Bs_ + (wc * 32 + ni * 8) * 128 + aoff);
    if (j + 2 < nk) { STAGE_A(ps, (j + 2) * 32); }
    __builtin_amdgcn_s_barrier();
    asm volatile("s_waitcnt lgkmcnt(0)" ::: "memory");
    __builtin_amdgcn_s_setprio(1);
#pragma unroll
    for (int mi = 0; mi < 4; ++mi)
#pragma unroll
      for (int ni = 0; ni < 4; ++ni)
        acc[mi][ni] = mfma16(af[mi], bf[ni], acc[mi][ni]);
    __builtin_amdgcn_s_setprio(0);
    __builtin_amdgcn_s_barrier();

    // ---- phase 1: M-frags 4..7 x N-frags 0..3 (B reused) ----
    bf16x8 af2[4];
#pragma unroll
    for (int mi = 0; mi < 4; ++mi)
      af2[mi] = *(const bf16x8*)(As_ + (wr * 64 + 32 + mi * 8) * 128 + aoff);
    if (j + 2 < nk) { STAGE_B(ps, (j + 2) * 32); }
    __builtin_amdgcn_s_barrier();
    asm volatile("s_waitcnt lgkmcnt(0)" ::: "memory");
    __builtin_amdgcn_s_setprio(1);
#pragma unroll
    for (int mi = 0; mi < 4; ++mi)
#pragma unroll
      for (int ni = 0; ni < 4; ++ni)
        acc[4 + mi][ni] = mfma16(af2[mi], bf[ni], acc[4 + mi][ni]);
    __builtin_amdgcn_s_setprio(0);

    if (j + 1 < nk) {
      if (j + 2 < nk) {
        asm volatile("s_waitcnt vmcnt(4)" ::: "memory");
      } else {
        asm volatile("s_waitcnt vmcnt(0)" ::: "memory");
      }
    }
    __builtin_amdgcn_s_barrier();
  }
#undef STAGE_A
#undef STAGE_B

  // ---------------- epilogue ----------------
  const int bufq = n0 >> 10;
  if (bufq < 2) {
    const float* bp = bufq ? bK : bQ;
    const float sc = bufq ? 1.0f : SCALE2;
#pragma unroll
    for (int ni = 0; ni < 4; ++ni) {
      int cn = (n0 & 1023) + wc * 64 + ni * 16 + r16;
      float bv = bp[cn];
#pragma unroll
      for (int mi = 0; mi < 8; ++mi) {
        int row = m0 + wr * 128 + mi * 16 + 4 * g;
#pragma unroll
        for (int jj = 0; jj < 4; ++jj)
          Cb[(size_t)bufq * 4194304u + (size_t)(row + jj) * 1024 + cn] =
              __builtin_bit_cast(unsigned short, (__bf16)((acc[mi][ni][jj] + bv) * sc));
      }
    }
  } else {
    // V: 256(s) x 256(hd) tile -> V^T in two 128-col passes through LDS
    unsigned short* T = (unsigned short*)LB;  // [128 cnl][264] shorts
    const int bb = m0 >> 11, s0g = m0 & 2047;
    unsigned short* Vt = Cb + 8388608u;
#pragma unroll
    for (int ph = 0; ph < 2; ++ph) {
      __syncthreads();
      if ((wc >> 1) == ph) {
#pragma unroll
        for (int ni = 0; ni < 4; ++ni) {
          int cnl = (wc & 1) * 64 + ni * 16 + r16;  // 0..127
          float bv = bV[(n0 & 1023) + ph * 128 + cnl];
#pragma unroll
          for (int mi = 0; mi < 8; ++mi) {
            int sl = wr * 128 + mi * 16 + 4 * g;
            union { __bf16 h4[4]; uint2 u; } cv;
#pragma unroll
            for (int jj = 0; jj < 4; ++jj) cv.h4[jj] = (__bf16)(acc[mi][ni][jj] + bv);
            *(uint2*)&T[cnl * 264 + sl] = cv.u;
          }
        }
      }
      __syncthreads();
#pragma unroll
      for (int q = 0; q < 8; ++q) {
        int idx2 = q * 512 + t;
        int cnl = idx2 >> 5, sch = idx2 & 31;
        int cng = (n0 & 1023) + ph * 128 + cnl;
        int hh = cng >> 6, d = cng & 63;
        short8 v = *(const short8*)&T[cnl * 264 + sch * 8];
        *(short8*)&Vt[(((size_t)((bb * 16 + hh) * 64 + d)) << 11) + s0g + sch * 8] = v;
      }
    }
  }
}

// ---------------- output-projection GEMM (r11 exact, unswizzled 128^2) --------------
__global__ __launch_bounds__(256) void gemm_out_kernel(
    const unsigned short* __restrict__ A, const unsigned short* __restrict__ Bt,
    float* __restrict__ Cf, const float* __restrict__ bias0, int M, int N, int K) {
  __shared__ __align__(16) unsigned short As[3][4096];
  __shared__ __align__(16) unsigned short Bs[3][4096];
  const int t = threadIdx.x, lane = t & 63;
  const int wid = t >> 6, wr = wid >> 1, wc = wid & 1;
  const int r16 = lane & 15, g = lane >> 4;
  const int m0 = blockIdx.y * 128, n0 = blockIdx.x * 128;
  const int nk = K >> 5;

  const int n1 = t, n2 = t + 256;
  const int r1g = t >> 2, c1g = (t & 3) * 8;
  const int r2g = (t + 256) >> 2;

  const unsigned short* ap1 = A + (size_t)(m0 + r1g) * K + c1g;
  const unsigned short* ap2 = A + (size_t)(m0 + r2g) * K + c1g;
  const unsigned short* bp1 = Bt + (size_t)(n0 + r1g) * K + c1g;
  const unsigned short* bp2 = Bt + (size_t)(n0 + r2g) * K + c1g;

#define GSTAGE(s)                          \
  gload_lds16(ap1, &As[s][n1 * 8]);        \
  gload_lds16(bp1, &Bs[s][n1 * 8]);        \
  gload_lds16(ap2, &As[s][n2 * 8]);        \
  gload_lds16(bp2, &Bs[s][n2 * 8]);        \
  ap1 += 32; ap2 += 32; bp1 += 32; bp2 += 32;

  f32x4 acc[4][4] = {};
  GSTAGE(0);
  GSTAGE(1);

  for (int kt = 0; kt < nk; ++kt) {
    const int cs = kt % 3;
    if (kt + 1 < nk) {
      asm volatile("s_waitcnt vmcnt(4)" ::: "memory");
    } else {
      asm volatile("s_waitcnt vmcnt(0)" ::: "memory");
    }
    __builtin_amdgcn_s_barrier();
    if (kt + 2 < nk) { GSTAGE((kt + 2) % 3); }

    bf16x8 af[4], bfr[4];
#pragma unroll
    for (int mi = 0; mi < 4; ++mi)
      af[mi] = *(const bf16x8*)&As[cs][(wr * 64 + mi * 16 + r16) * 32 + g * 8];
#pragma unroll
    for (int ni = 0; ni < 4; ++ni)
      bfr[ni] = *(const bf16x8*)&Bs[cs][(wc * 64 + ni * 16 + r16) * 32 + g * 8];
    __builtin_amdgcn_s_setprio(1);
#pragma unroll
    for (int mi = 0; mi < 4; ++mi)
#pragma unroll
      for (int ni = 0; ni < 4; ++ni)
        acc[mi][ni] = mfma16(af[mi], bfr[ni], acc[mi][ni]);
    __builtin_amdgcn_s_setprio(0);
  }
#undef GSTAGE

#pragma unroll
  for (int ni = 0; ni < 4; ++ni) {
    int col = n0 + wc * 64 + ni * 16 + r16;
    float bv = bias0[col];
#pragma unroll
    for (int mi = 0; mi < 4; ++mi) {
      int rowb = m0 + wr * 64 + mi * 16 + 4 * g;
#pragma unroll
      for (int j = 0; j < 4; ++j)
        Cf[(size_t)(rowb + j) * N + col] = acc[mi][ni][j] + bv;
    }
  }
}

// ---------------- flash attention v11 (best, unchanged): 32x32 MFMA, kv-split -------
__global__ __launch_bounds__(256, 2) void attn_kernel(
    const unsigned short* __restrict__ Qm, const unsigned short* __restrict__ Km,
    const unsigned short* __restrict__ VtG, unsigned short* __restrict__ Om) {
  const int t = threadIdx.x, lane = t & 63, w = t >> 6;
  const int l31 = lane & 31, hi = lane >> 5;
  const int bid = blockIdx.x;
  const int xk = bid & 7, slot = bid >> 3;
  const int grp = xk * 4 + (slot >> 4);  // (b,h) group, 4 per XCD
  const int mq = slot & 15;
  const int h = grp & 15, b = grp >> 4;

  __shared__ __align__(16) char LB[71680];
  float* R = (float*)LB;
  float* ls = (float*)(LB + 69632);

  const unsigned short* Kbase = Km + (size_t)(b * S_LEN) * DM + h * HD;
  const unsigned short* Vbase = VtG + (size_t)((b * NH + h) * HD) * S_LEN;

  const int kg = ((t & 7) ^ ((t >> 3) & 7)) * 8;
  const int kr0 = t >> 3;
  const int vg = ((t & 15) ^ ((t >> 4) & 15)) * 8;
  const int vr0 = t >> 4;

  auto stage = [&](int cs, int kv0) {
    unsigned short* kd = (unsigned short*)(LB + cs * 16384) + t * 8;
    unsigned short* vd = (unsigned short*)(LB + 32768 + cs * 16384) + t * 8;
#pragma unroll
    for (int p = 0; p < 4; ++p)
      gload_lds16(Kbase + (size_t)(kv0 + kr0 + 32 * p) * DM + kg, kd + 2048 * p);
#pragma unroll
    for (int p = 0; p < 4; ++p)
      gload_lds16(Vbase + (size_t)(vr0 + 16 * p) * S_LEN + kv0 + vg, vd + 2048 * p);
  };

  for (int half = 0; half < 2; ++half) {
    const int T = half ? 31 - mq : mq;
    const int q0 = T * 64;

    bf16x8 qfr[2][4];
#pragma unroll
    for (int qt = 0; qt < 2; ++qt) {
      const unsigned short* Qp =
          Qm + (size_t)(b * S_LEN + q0 + qt * 32 + l31) * DM + h * HD;
#pragma unroll
      for (int kc = 0; kc < 4; ++kc)
        qfr[qt][kc] = *(const bf16x8*)(Qp + kc * 16 + hi * 8);
    }

    f32x16 oacc[2][2] = {};
    float lsum0 = 0.f, lsum1 = 0.f;
    const int ntk = (T >> 1) + 1;

    stage(0, 0);

    for (int kt = 0; kt < ntk; ++kt) {
      const int cs = kt & 1;
      asm volatile("s_waitcnt vmcnt(0)" ::: "memory");
      __builtin_amdgcn_s_barrier();
      if (kt + 1 < ntk) stage(cs ^ 1, (kt + 1) * 128);

      const int kv0w = kt * 128 + w * 32;
      if (kv0w <= q0 + 63) {
        const unsigned short* Ksb = (const unsigned short*)(LB + cs * 16384);
        const unsigned short* Vsb = (const unsigned short*)(LB + 32768 + cs * 16384);

        bf16x8 kf[4];
#pragma unroll
        for (int kc = 0; kc < 4; ++kc)
          kf[kc] = *(const bf16x8*)&Ksb[(w * 32 + l31) * 64 +
                                        (((hi + 2 * kc) ^ (lane & 7)) * 8)];
        bool act0 = false, act1 = false;
        bf16x8 pfr[2][2];
#pragma unroll
        for (int qt = 0; qt < 2; ++qt) {
          const bool act = (kv0w <= q0 + qt * 32 + 31);
          if (qt == 0) act0 = act; else act1 = act;
          if (!act) continue;
          f32x16 st = {};
          __builtin_amdgcn_s_setprio(1);
#pragma unroll
          for (int kc = 0; kc < 4; ++kc) st = mfma32(kf[kc], qfr[qt][kc], st);
          __builtin_amdgcn_s_setprio(0);

          const bool needmask = (kv0w + 31 > q0 + qt * 32);
          const int qg = q0 + qt * 32 + l31;
          float p[16];
          float ps = 0.f;
#pragma unroll
          for (int r = 0; r < 16; ++r) {
            int row = (r & 3) + 8 * (r >> 2) + 4 * hi;
            float v = __builtin_amdgcn_exp2f(st[r] - M2FIX);
            if (needmask && (kv0w + row > qg)) v = 0.f;
            p[r] = v;
            ps += v;
          }
          if (qt == 0) lsum0 += ps; else lsum1 += ps;

          unsigned pw[8];
#pragma unroll
          for (int r = 0; r < 8; ++r) {
            union { __bf16 h2[2]; unsigned u; } cv;
            cv.h2[0] = (__bf16)p[2 * r];
            cv.h2[1] = (__bf16)p[2 * r + 1];
            pw[r] = cv.u;
          }
          {
            auto s0 = __builtin_amdgcn_permlane32_swap(pw[0], pw[2], false, false);
            pw[0] = s0[0]; pw[2] = s0[1];
            auto s1 = __builtin_amdgcn_permlane32_swap(pw[1], pw[3], false, false);
            pw[1] = s1[0]; pw[3] = s1[1];
            auto s2 = __builtin_amdgcn_permlane32_swap(pw[4], pw[6], false, false);
            pw[4] = s2[0]; pw[6] = s2[1];
            auto s3 = __builtin_amdgcn_permlane32_swap(pw[5], pw[7], false, false);
            pw[5] = s3[0]; pw[7] = s3[1];
          }
          union { unsigned u[4]; bf16x8 v; } f0, f1;
          f0.u[0] = pw[0]; f0.u[1] = pw[1]; f0.u[2] = pw[2]; f0.u[3] = pw[3];
          f1.u[0] = pw[4]; f1.u[1] = pw[5]; f1.u[2] = pw[6]; f1.u[3] = pw[7];
          pfr[qt][0] = f0.v;
          pfr[qt][1] = f1.v;
        }

        bf16x8 vf[2][2];
#pragma unroll
        for (int dt = 0; dt < 2; ++dt)
#pragma unroll
          for (int ks = 0; ks < 2; ++ks)
            vf[dt][ks] = *(const bf16x8*)&Vsb[(dt * 32 + l31) * 128 +
                                              (((4 * w + 2 * ks + hi) ^ (lane & 15)) * 8)];
        __builtin_amdgcn_s_setprio(1);
        if (act0) {
#pragma unroll
          for (int dt = 0; dt < 2; ++dt) {
            oacc[dt][0] = mfma32(vf[dt][0], pfr[0][0], oacc[dt][0]);
            oacc[dt][0] = mfma32(vf[dt][1], pfr[0][1], oacc[dt][0]);
          }
        }
        if (act1) {
#pragma unroll
          for (int dt = 0; dt < 2; ++dt) {
            oacc[dt][1] = mfma32(vf[dt][0], pfr[1][0], oacc[dt][1]);
            oacc[dt][1] = mfma32(vf[dt][1], pfr[1][1], oacc[dt][1]);
          }
        }
        __builtin_amdgcn_s_setprio(0);
      }
    }

    __syncthreads();
    float* Rw = R + w * 4352;
#pragma unroll
    for (int dt = 0; dt < 2; ++dt)
#pragma unroll
      for (int qt = 0; qt < 2; ++qt) {
        int q = qt * 32 + l31;
#pragma unroll
        for (int r = 0; r < 16; r += 2) {
          int d = dt * 32 + ((r & 3) + 8 * (r >> 2)) + 4 * hi;
          float2 v2;
          v2.x = oacc[dt][qt][r];
          v2.y = oacc[dt][qt][r + 1];
          *(float2*)&Rw[q * 68 + d] = v2;
        }
      }
    ls[(w * 64 + l31) * 2 + hi] = lsum0;
    ls[(w * 64 + 32 + l31) * 2 + hi] = lsum1;
    __syncthreads();

    const int rq = t >> 2, dq = (t & 3) * 16;
    f32x4 a0 = {}, a1 = {}, a2 = {}, a3 = {};
#pragma unroll
    for (int w4 = 0; w4 < 4; ++w4) {
      const float* Rb = R + w4 * 4352 + rq * 68 + dq;
      a0 += *(const f32x4*)&Rb[0];
      a1 += *(const f32x4*)&Rb[4];
      a2 += *(const f32x4*)&Rb[8];
      a3 += *(const f32x4*)&Rb[12];
    }
    float s = 0.f;
#pragma unroll
    for (int w4 = 0; w4 < 4; ++w4)
      s += ls[(w4 * 64 + rq) * 2] + ls[(w4 * 64 + rq) * 2 + 1];
    float li = 1.0f / s;
    unsigned short* op = Om + (size_t)(b * S_LEN + q0 + rq) * DM + h * HD + dq;
    union { __bf16 hh[8]; uint4 u; } o0, o1;
#pragma unroll
    for (int i = 0; i < 4; ++i) {
      o0.hh[i] = (__bf16)(a0[i] * li);
      o0.hh[4 + i] = (__bf16)(a1[i] * li);
      o1.hh[i] = (__bf16)(a2[i] * li);
      o1.hh[4 + i] = (__bf16)(a3[i] * li);
    }
    *(uint4*)op = o0.u;
    *(uint4*)(op + 8) = o1.u;
    __syncthreads();
  }
}

extern "C" void kernel_launch(void* const* d_in, const int* in_sizes, int n_in,
                              void* d_out, int out_size, void* d_ws, size_t ws_size,
                              hipStream_t stream) {
  (void)in_sizes; (void)n_in; (void)out_size; (void)ws_size;
  const float* x  = (const float*)d_in[0];
  const float* WQ = (const float*)d_in[1];
  const float* WK = (const float*)d_in[2];
  const float* WV = (const float*)d_in[3];
  const float* WO = (const float*)d_in[4];
  const float* bQ = (const float*)d_in[5];
  const float* bK = (const float*)d_in[6];
  const float* bV = (const float*)d_in[7];
  const float* bO = (const float*)d_in[8];

  char* ws = (char*)d_ws;
  unsigned short* xb  = (unsigned short*)(ws);               // 8 MiB (x bf16)
  unsigned short* wt  = (unsigned short*)(ws + (8u << 20));  // 8 MiB (Wq|Wk|Wv|Wo)^T
  unsigned short* qb  = (unsigned short*)(ws + (16u << 20)); // 24 MiB (Q | K | V^T)
  unsigned short* hsb = (unsigned short*)(ws + (40u << 20)); // 8 MiB (attn out)

  // fused prep: x cast (z=0) + 4 weight transposes (z=1..4)
  prep_kernel<<<dim3(32, 32, 5), 256, 0, stream>>>(x, WQ, WK, WV, WO, xb, wt);
  // fused QKV projection (256^2 phase-split): Q pre-scaled, V^T epilogue
  gemm_qkv256_kernel<<<192, 512, 0, stream>>>(xb, wt, qb, bQ, bK, bV);
  attn_kernel<<<512, 256, 0, stream>>>(qb, qb + 4194304u, qb + 8388608u, hsb);
  // output projection: f32 out (r11 unswizzled 128^2)
  gemm_out_kernel<<<dim3(8, 32), 256, 0, stream>>>(
      hsb, wt + 3u * 1048576u, (float*)d_out, bO, M_ROWS, DM, DM);
}